// Round 1
// baseline (8290.810 us; speedup 1.0000x reference)
//
#include <hip/hip_runtime.h>
#include <hip/hip_bf16.h>
#include <stdint.h>

#define B_   64
#define T_   1024
#define D_   300
#define H_   512
#define G4H  2048
#define KP   320   // K padded to multiple of 32 for the x-proj GEMM

typedef __attribute__((ext_vector_type(8))) short short8;   // 8 x bf16 (4 VGPRs)
typedef __attribute__((ext_vector_type(4))) float f32x4;

__device__ __forceinline__ unsigned short f2bf(float v) {
    __hip_bfloat16 h = __float2bfloat16(v);
    return *reinterpret_cast<unsigned short*>(&h);
}
__device__ __forceinline__ float bf2f(unsigned short u) {
    return __uint_as_float(((unsigned)u) << 16);
}
__device__ __forceinline__ float sigm(float x) { return 1.f / (1.f + __expf(-x)); }
__device__ __forceinline__ float tanhfast(float x) {
    float e = __expf(2.f * x);            // inf-safe: x>>0 -> 1, x<<0 -> -1
    return 1.f - 2.f / (e + 1.f);
}

#define ASYNC16(g, l)                                                        \
    __builtin_amdgcn_global_load_lds(                                        \
        (const __attribute__((address_space(1))) void*)(g),                  \
        (__attribute__((address_space(3))) void*)(l), 16, 0, 0)

// ---------------------------------------------------------------------------
// Kernel 1: essays fp32 [65536][300] -> bf16 [65536][320] (zero-padded K)
// ---------------------------------------------------------------------------
__global__ void cvt_essays(const float* __restrict__ es, unsigned short* __restrict__ Ab) {
    unsigned i = blockIdx.x * 256u + threadIdx.x;       // exactly 65536*320 threads
    unsigned row = i / KP;
    unsigned col = i - row * KP;
    float v = (col < D_) ? es[(size_t)row * D_ + col] : 0.f;
    Ab[i] = f2bf(v);
}

// ---------------------------------------------------------------------------
// Kernel 2: Wx transpose+pad -> bf16 WxT[2048][320]; zero h ping-pong + counters
// ---------------------------------------------------------------------------
__global__ void cvt_misc(const float* __restrict__ Wl, unsigned short* __restrict__ Bt,
                         unsigned short* __restrict__ hbuf, unsigned int* __restrict__ cnt) {
    unsigned i = blockIdx.x * 256u + threadIdx.x;       // exactly 2048*320 threads
    {
        unsigned n = i / KP, k = i - n * KP;
        float v = (k < D_) ? Wl[(size_t)k * G4H + n] : 0.f;   // Wx rows 0..299
        Bt[i] = f2bf(v);
    }
    if (i < 2u * 64u * 512u) hbuf[i] = 0;               // both ping-pong buffers
    if (i < 256u) cnt[i] = 0u;                          // group barrier counters
}

// ---------------------------------------------------------------------------
// Kernel 3: x_proj GEMM  C[65536][2048] = A[65536][320] @ WxT^T + b_lstm (bf16 out)
// m97 structure: 128x128 tile, BK=32, global_load_lds width 16, 4 waves 2x2.
// ---------------------------------------------------------------------------
__global__ __launch_bounds__(256) void gemm_xp(
    const unsigned short* __restrict__ Ab,   // [65536][320] bf16
    const unsigned short* __restrict__ Bt,   // [2048][320]  bf16 (WxT)
    const float* __restrict__ bias,          // [2048]
    unsigned short* __restrict__ Cb)         // [65536][2048] bf16
{
    __shared__ __align__(16) unsigned short Al[128 * 32];
    __shared__ __align__(16) unsigned short Bl[128 * 32];
    const int tid = threadIdx.x;
    const int w = tid >> 6, lane = tid & 63;
    const int ln = lane & 15, q = lane >> 4;
    const int bx = blockIdx.x;
    const int m0 = (bx >> 4) * 128;          // consecutive blocks share the A tile
    const int n0 = (bx & 15) * 128;
    const int wr = w >> 1, wc = w & 1;

    f32x4 acc[4][4];
#pragma unroll
    for (int i = 0; i < 4; i++)
#pragma unroll
        for (int j = 0; j < 4; j++) acc[i][j] = (f32x4){0.f, 0.f, 0.f, 0.f};

    for (int k0 = 0; k0 < KP; k0 += 32) {
#pragma unroll
        for (int it = 0; it < 2; ++it) {
            int s = it * 4 + w;              // wave-uniform segment id
            int c = s * 64 + lane;           // 16B chunk id, 0..511
            int r = c >> 2;                  // tile row 0..127
            int ko = (c & 3) * 8;            // k offset in elements
            ASYNC16(Ab + (size_t)(m0 + r) * KP + k0 + ko, &Al[s * 512]);
            ASYNC16(Bt + (size_t)(n0 + r) * KP + k0 + ko, &Bl[s * 512]);
        }
        __syncthreads();
        short8 af[4], bf[4];
#pragma unroll
        for (int mt = 0; mt < 4; ++mt)
            af[mt] = *(const short8*)&Al[(wr * 64 + mt * 16 + ln) * 32 + q * 8];
#pragma unroll
        for (int nt = 0; nt < 4; ++nt)
            bf[nt] = *(const short8*)&Bl[(wc * 64 + nt * 16 + ln) * 32 + q * 8];
#pragma unroll
        for (int mt = 0; mt < 4; ++mt)
#pragma unroll
            for (int nt = 0; nt < 4; ++nt)
                acc[mt][nt] = __builtin_amdgcn_mfma_f32_16x16x32_bf16(af[mt], bf[nt], acc[mt][nt], 0, 0, 0);
        __syncthreads();
    }
#pragma unroll
    for (int mt = 0; mt < 4; ++mt) {
#pragma unroll
        for (int nt = 0; nt < 4; ++nt) {
            int col = n0 + wc * 64 + nt * 16 + ln;
            float bb = bias[col];
#pragma unroll
            for (int r = 0; r < 4; ++r) {
                int row = m0 + wr * 64 + mt * 16 + q * 4 + r;   // C/D: col=lane&15, row=quad*4+reg
                Cb[(size_t)row * G4H + col] = f2bf(acc[mt][nt][r] + bb);
            }
        }
    }
}

// ---------------------------------------------------------------------------
// Kernel 4: persistent LSTM recurrence.
// 4 batch groups x 32 j-slice blocks = 128 blocks, 1/CU, all co-resident.
// Each block: Wh slice (512x64, transposed [col][k]) resident in LDS bf16.
// Per step: stage h (16x512 bf16) -> LDS, 16-chain MFMA per gate-wave,
// elementwise gates in fp32, write new_h slice, group barrier via atomic cnt.
// ---------------------------------------------------------------------------
__global__ __launch_bounds__(256, 1) void lstm_rec(
    const float* __restrict__ Wl,            // [812][2048] fp32
    const unsigned short* __restrict__ xp,   // [65536][2048] bf16 (x_proj + bias)
    unsigned short* __restrict__ hbuf,       // [2][64][512] bf16 ping-pong
    float* __restrict__ hmean,               // [64][512] fp32
    unsigned int* __restrict__ cnt)          // [4 * 64] monotonic counters
{
    __shared__ __align__(16) unsigned short WhT[64 * 520];   // [col][k], pad 520
    __shared__ __align__(16) unsigned short hl[16 * 520];    // [b][k], pad 520
    __shared__ float gbuf[4 * 16 * 17];                      // [gate][b][j], pad 17

    const int tid = threadIdx.x;
    const int bid = blockIdx.x;
    const int g   = bid >> 5;          // batch group 0..3
    const int j0  = (bid & 31) * 16;   // j-slice base
    const int bg  = g * 16;            // batch row base
    const int wv  = tid >> 6, lane = tid & 63, ln = lane & 15, q = lane >> 4;

    // one-time: load + transpose + bf16-convert this block's Wh slice
    {
        const int c  = tid & 63;                              // local col (gate*16+jj)
        const int gc = (c >> 4) * 512 + j0 + (c & 15);        // global gate column
        for (int k = tid >> 6; k < 512; k += 4)
            WhT[c * 520 + k] = f2bf(Wl[(size_t)(300 + k) * G4H + gc]);
    }
    const int b = tid >> 4;            // local batch row 0..15
    const int j = tid & 15;            // local j 0..15
    float c_st = 0.f, hsum = 0.f;
    unsigned int* myc = cnt + g * 64;  // 256B-spaced counter per group

    for (int t = 0; t < T_; ++t) {
        // stage h_t from hbuf[t&1] (t=0: zeros) into LDS
        {
            const int row = tid >> 4;
            const int cb  = (tid & 15) * 32;
            const uint4* src = (const uint4*)(hbuf + (size_t)(t & 1) * (64 * 512)
                                              + (size_t)(bg + row) * 512 + cb);
            uint4* dst = (uint4*)&hl[row * 520 + cb];
#pragma unroll
            for (int i = 0; i < 4; i++) dst[i] = src[i];
        }
        __syncthreads();

        // wave wv computes gate wv: 16(batch) x 16(j), K=512
        f32x4 acc = (f32x4){0.f, 0.f, 0.f, 0.f};
#pragma unroll
        for (int kk = 0; kk < 16; ++kk) {
            short8 a  = *(const short8*)&hl[ln * 520 + kk * 32 + q * 8];
            short8 bb = *(const short8*)&WhT[(wv * 16 + ln) * 520 + kk * 32 + q * 8];
            acc = __builtin_amdgcn_mfma_f32_16x16x32_bf16(a, bb, acc, 0, 0, 0);
        }
#pragma unroll
        for (int r = 0; r < 4; ++r)
            gbuf[wv * 272 + (q * 4 + r) * 17 + ln] = acc[r];
        __syncthreads();

        // elementwise: thread (b, j)
        const unsigned short* xq = xp + ((size_t)(bg + b) * T_ + t) * G4H + j0 + j;
        float ai  = gbuf[0 * 272 + b * 17 + j] + bf2f(xq[0]);
        float aj  = gbuf[1 * 272 + b * 17 + j] + bf2f(xq[512]);
        float af_ = gbuf[2 * 272 + b * 17 + j] + bf2f(xq[1024]);
        float ao  = gbuf[3 * 272 + b * 17 + j] + bf2f(xq[1536]);
        float si = sigm(ai), tj = tanhfast(aj);
        float sf = sigm(af_ + 1.0f), so = sigm(ao);
        c_st = c_st * sf + si * tj;
        float h = tanhfast(c_st) * so;
        hsum += h;
        hbuf[(size_t)((t + 1) & 1) * (64 * 512) + (size_t)(bg + b) * 512 + j0 + j] = f2bf(h);

        if (t < T_ - 1) {
            __syncthreads();                       // drains vmcnt (stores) before arrival
            if (tid == 0) {
                __threadfence();                   // device-scope release
                atomicAdd(myc, 1u);
                unsigned target = 32u * (unsigned)(t + 1);
                while (__hip_atomic_load(myc, __ATOMIC_RELAXED, __HIP_MEMORY_SCOPE_AGENT) < target) {}
                __threadfence();                   // device-scope acquire
            }
            __syncthreads();
        }
    }
    hmean[(size_t)(bg + b) * 512 + j0 + j] = hsum * (1.f / 1024.f);
}

// ---------------------------------------------------------------------------
// Kernel 5: preds = sigmoid(hmean @ W_dense + b_dense), one wave per batch row
// ---------------------------------------------------------------------------
__global__ void dense_out(const float* __restrict__ hmean, const float* __restrict__ Wd,
                          const float* __restrict__ bd, float* __restrict__ out) {
    int bb = blockIdx.x;
    int lane = threadIdx.x;
    float p = 0.f;
    for (int e = lane; e < H_; e += 64) p += hmean[(size_t)bb * H_ + e] * Wd[e];
#pragma unroll
    for (int off = 32; off; off >>= 1) p += __shfl_down(p, off);
    if (lane == 0) out[bb] = 1.f / (1.f + __expf(-(p + bd[0])));
}

// ---------------------------------------------------------------------------
extern "C" void kernel_launch(void* const* d_in, const int* in_sizes, int n_in,
                              void* d_out, int out_size, void* d_ws, size_t ws_size,
                              hipStream_t stream) {
    const float* essays  = (const float*)d_in[0];
    const float* W_lstm  = (const float*)d_in[1];
    const float* b_lstm  = (const float*)d_in[2];
    const float* W_dense = (const float*)d_in[3];
    const float* b_dense = (const float*)d_in[4];
    float* out = (float*)d_out;

    char* ws = (char*)d_ws;
    unsigned short* xp   = (unsigned short*)(ws);                   // 65536*2048*2 = 256 MB
    unsigned short* Ab   = (unsigned short*)(ws + 268435456ull);    // 65536*320*2  = 40 MB
    unsigned short* Bt   = (unsigned short*)(ws + 310378496ull);    // 2048*320*2   = 1.25 MB
    unsigned short* hbuf = (unsigned short*)(ws + 311689216ull);    // 2*64*512*2   = 128 KB
    float*          hm   = (float*)(ws + 311820288ull);             // 64*512*4     = 128 KB
    unsigned int*   cnt  = (unsigned int*)(ws + 311951360ull);      // 256*4        = 1 KB

    hipLaunchKernelGGL(cvt_essays, dim3(81920), dim3(256), 0, stream, essays, Ab);
    hipLaunchKernelGGL(cvt_misc,   dim3(2560),  dim3(256), 0, stream, W_lstm, Bt, hbuf, cnt);
    hipLaunchKernelGGL(gemm_xp,    dim3(8192),  dim3(256), 0, stream, Ab, Bt, b_lstm, xp);
    hipLaunchKernelGGL(lstm_rec,   dim3(128),   dim3(256), 0, stream, W_lstm, xp, hbuf, hm, cnt);
    hipLaunchKernelGGL(dense_out,  dim3(64),    dim3(64),  0, stream, hm, W_dense, b_dense, out);
}

// Round 2
// 4119.269 us; speedup vs baseline: 2.0127x; 2.0127x over previous
//
#include <hip/hip_runtime.h>
#include <hip/hip_bf16.h>
#include <stdint.h>

#define B_   64
#define T_   1024
#define D_   300
#define H_   512
#define G4H  2048
#define KP   320   // K padded to multiple of 32 for the x-proj GEMM

typedef __attribute__((ext_vector_type(8))) short short8;   // 8 x bf16 (4 VGPRs)
typedef __attribute__((ext_vector_type(4))) float f32x4;
typedef unsigned long long ull;

__device__ __forceinline__ unsigned short f2bf(float v) {
    __hip_bfloat16 h = __float2bfloat16(v);
    return *reinterpret_cast<unsigned short*>(&h);
}
__device__ __forceinline__ float bf2f(unsigned short u) {
    return __uint_as_float(((unsigned)u) << 16);
}
__device__ __forceinline__ float sigm(float x) { return 1.f / (1.f + __expf(-x)); }
__device__ __forceinline__ float tanhfast(float x) {
    float e = __expf(2.f * x);            // inf-safe: x>>0 -> 1, x<<0 -> -1
    return 1.f - 2.f / (e + 1.f);
}

#define ASYNC16(g, l)                                                        \
    __builtin_amdgcn_global_load_lds(                                        \
        (const __attribute__((address_space(1))) void*)(g),                  \
        (__attribute__((address_space(3))) void*)(l), 16, 0, 0)

// ---------------------------------------------------------------------------
// Kernel 1: essays fp32 [65536][300] -> bf16 [65536][320] (zero-padded K)
// ---------------------------------------------------------------------------
__global__ void cvt_essays(const float* __restrict__ es, unsigned short* __restrict__ Ab) {
    unsigned i = blockIdx.x * 256u + threadIdx.x;       // exactly 65536*320 threads
    unsigned row = i / KP;
    unsigned col = i - row * KP;
    float v = (col < D_) ? es[(size_t)row * D_ + col] : 0.f;
    Ab[i] = f2bf(v);
}

// ---------------------------------------------------------------------------
// Kernel 2: Wx transpose+pad -> bf16 WxT[2048][320]; zero h ping-pong + counters
// ---------------------------------------------------------------------------
__global__ void cvt_misc(const float* __restrict__ Wl, unsigned short* __restrict__ Bt,
                         unsigned short* __restrict__ hbuf, unsigned int* __restrict__ cnt) {
    unsigned i = blockIdx.x * 256u + threadIdx.x;       // exactly 2048*320 threads
    {
        unsigned n = i / KP, k = i - n * KP;
        float v = (k < D_) ? Wl[(size_t)k * G4H + n] : 0.f;   // Wx rows 0..299
        Bt[i] = f2bf(v);
    }
    if (i < 2u * 64u * 512u) hbuf[i] = 0;               // both ping-pong buffers
    if (i < 256u) cnt[i] = 0u;                          // group barrier counters
}

// ---------------------------------------------------------------------------
// Kernel 3: x_proj GEMM  C[65536][2048] = A[65536][320] @ WxT^T + b_lstm (bf16 out)
// ---------------------------------------------------------------------------
__global__ __launch_bounds__(256) void gemm_xp(
    const unsigned short* __restrict__ Ab,   // [65536][320] bf16
    const unsigned short* __restrict__ Bt,   // [2048][320]  bf16 (WxT)
    const float* __restrict__ bias,          // [2048]
    unsigned short* __restrict__ Cb)         // [65536][2048] bf16
{
    __shared__ __align__(16) unsigned short Al[128 * 32];
    __shared__ __align__(16) unsigned short Bl[128 * 32];
    const int tid = threadIdx.x;
    const int w = tid >> 6, lane = tid & 63;
    const int ln = lane & 15, q = lane >> 4;
    const int bx = blockIdx.x;
    const int m0 = (bx >> 4) * 128;          // consecutive blocks share the A tile
    const int n0 = (bx & 15) * 128;
    const int wr = w >> 1, wc = w & 1;

    f32x4 acc[4][4];
#pragma unroll
    for (int i = 0; i < 4; i++)
#pragma unroll
        for (int j = 0; j < 4; j++) acc[i][j] = (f32x4){0.f, 0.f, 0.f, 0.f};

    for (int k0 = 0; k0 < KP; k0 += 32) {
#pragma unroll
        for (int it = 0; it < 2; ++it) {
            int s = it * 4 + w;              // wave-uniform segment id
            int c = s * 64 + lane;           // 16B chunk id, 0..511
            int r = c >> 2;                  // tile row 0..127
            int ko = (c & 3) * 8;            // k offset in elements
            ASYNC16(Ab + (size_t)(m0 + r) * KP + k0 + ko, &Al[s * 512]);
            ASYNC16(Bt + (size_t)(n0 + r) * KP + k0 + ko, &Bl[s * 512]);
        }
        __syncthreads();
        short8 af[4], bf[4];
#pragma unroll
        for (int mt = 0; mt < 4; ++mt)
            af[mt] = *(const short8*)&Al[(wr * 64 + mt * 16 + ln) * 32 + q * 8];
#pragma unroll
        for (int nt = 0; nt < 4; ++nt)
            bf[nt] = *(const short8*)&Bl[(wc * 64 + nt * 16 + ln) * 32 + q * 8];
#pragma unroll
        for (int mt = 0; mt < 4; ++mt)
#pragma unroll
            for (int nt = 0; nt < 4; ++nt)
                acc[mt][nt] = __builtin_amdgcn_mfma_f32_16x16x32_bf16(af[mt], bf[nt], acc[mt][nt], 0, 0, 0);
        __syncthreads();
    }
#pragma unroll
    for (int mt = 0; mt < 4; ++mt) {
#pragma unroll
        for (int nt = 0; nt < 4; ++nt) {
            int col = n0 + wc * 64 + nt * 16 + ln;
            float bb = bias[col];
#pragma unroll
            for (int r = 0; r < 4; ++r) {
                int row = m0 + wr * 64 + mt * 16 + q * 4 + r;   // C/D: col=lane&15, row=quad*4+reg
                Cb[(size_t)row * G4H + col] = f2bf(acc[mt][nt][r] + bb);
            }
        }
    }
}

// ---------------------------------------------------------------------------
// Kernel 4: persistent LSTM recurrence.
// h exchange via AGENT-scope (device) loads/stores: bypass L1/L2, complete at
// the coherence point (L3). No threadfence / wbl2 / buffer_inv anywhere.
// Ordering: __syncthreads() drains vmcnt (stores complete at coherence point)
// before tid0's relaxed agent-scope counter bump; readers observe counter then
// issue agent-scope h loads (also served at the coherence point).
// ---------------------------------------------------------------------------
__global__ __launch_bounds__(256, 1) void lstm_rec(
    const float* __restrict__ Wl,            // [812][2048] fp32
    const unsigned short* __restrict__ xp,   // [65536][2048] bf16 (x_proj + bias)
    unsigned short* __restrict__ hbuf,       // [2][64][512] bf16 ping-pong
    float* __restrict__ hmean,               // [64][512] fp32
    unsigned int* __restrict__ cnt)          // [4 * 64] monotonic counters
{
    __shared__ __align__(16) unsigned short WhT[64 * 520];   // [col][k], pad 520
    __shared__ __align__(16) unsigned short hl[16 * 520];    // [b][k], pad 520
    __shared__ float gbuf[4 * 16 * 17];                      // [gate][b][j], pad 17

    const int tid = threadIdx.x;
    const int bid = blockIdx.x;
    const int g   = bid >> 5;          // batch group 0..3
    const int j0  = (bid & 31) * 16;   // j-slice base
    const int bg  = g * 16;            // batch row base
    const int wv  = tid >> 6, lane = tid & 63, ln = lane & 15, q = lane >> 4;

    // one-time: load + transpose + bf16-convert this block's Wh slice
    {
        const int c  = tid & 63;                              // local col (gate*16+jj)
        const int gc = (c >> 4) * 512 + j0 + (c & 15);        // global gate column
        for (int k = tid >> 6; k < 512; k += 4)
            WhT[c * 520 + k] = f2bf(Wl[(size_t)(300 + k) * G4H + gc]);
    }
    const int b = tid >> 4;            // local batch row 0..15
    const int j = tid & 15;            // local j 0..15
    float c_st = 0.f, hsum = 0.f;
    unsigned int* myc = cnt + g * 64;  // 256B-spaced counter per group

    // xp double-buffer: xc holds step-t values, xn prefetches t+1
    const unsigned short* xbase = xp + (size_t)(bg + b) * T_ * G4H + j0 + j;
    unsigned short xc0, xc1, xc2, xc3, xn0, xn1, xn2, xn3;
    {
        const unsigned short* q_ = xbase;
        xc0 = q_[0]; xc1 = q_[512]; xc2 = q_[1024]; xc3 = q_[1536];
    }

    unsigned long long* const hl8 = (unsigned long long*)hl;

    for (int t = 0; t < T_; ++t) {
        // stage h_t from hbuf[t&1] into LDS via agent-scope 8B loads
        {
            const ull* hb8 = (const ull*)(hbuf + (size_t)(t & 1) * 32768 + (size_t)bg * 512);
#pragma unroll
            for (int i = 0; i < 8; ++i) {
                int c = tid + (i << 8);                       // 0..2047 8B chunks
                ull v = __hip_atomic_load(hb8 + c, __ATOMIC_RELAXED, __HIP_MEMORY_SCOPE_AGENT);
                hl8[(c >> 7) * 130 + (c & 127)] = v;          // row pad = 130 ull
            }
        }
        __syncthreads();

        // wave wv computes gate wv: 16(batch) x 16(j), K=512
        f32x4 acc = (f32x4){0.f, 0.f, 0.f, 0.f};
#pragma unroll
        for (int kk = 0; kk < 16; ++kk) {
            short8 a  = *(const short8*)&hl[ln * 520 + kk * 32 + q * 8];
            short8 bb = *(const short8*)&WhT[(wv * 16 + ln) * 520 + kk * 32 + q * 8];
            acc = __builtin_amdgcn_mfma_f32_16x16x32_bf16(a, bb, acc, 0, 0, 0);
        }
#pragma unroll
        for (int r = 0; r < 4; ++r)
            gbuf[wv * 272 + (q * 4 + r) * 17 + ln] = acc[r];

        // prefetch xp for t+1 (latency hidden under the sync + elementwise)
        {
            const unsigned short* q_ = xbase + (size_t)((t + 1 < T_) ? t + 1 : t) * G4H;
            xn0 = q_[0]; xn1 = q_[512]; xn2 = q_[1024]; xn3 = q_[1536];
        }
        __syncthreads();

        // elementwise: thread (b, j)
        float ai  = gbuf[0 * 272 + b * 17 + j] + bf2f(xc0);
        float aj  = gbuf[1 * 272 + b * 17 + j] + bf2f(xc1);
        float af_ = gbuf[2 * 272 + b * 17 + j] + bf2f(xc2);
        float ao  = gbuf[3 * 272 + b * 17 + j] + bf2f(xc3);
        float si = sigm(ai), tj = tanhfast(aj);
        float sf = sigm(af_ + 1.0f), so = sigm(ao);
        c_st = c_st * sf + si * tj;
        float h = tanhfast(c_st) * so;
        hsum += h;
        xc0 = xn0; xc1 = xn1; xc2 = xn2; xc3 = xn3;

        // pack 4 bf16 -> 8B and store agent-scope (j%4==0 lanes)
        {
            unsigned u0 = f2bf(h);
            unsigned u1 = __shfl_down(u0, 1);
            unsigned u2 = __shfl_down(u0, 2);
            unsigned u3 = __shfl_down(u0, 3);
            if ((j & 3) == 0) {
                ull pk = (ull)(u0 | (u1 << 16)) | ((ull)(u2 | (u3 << 16)) << 32);
                ull* dst = (ull*)(hbuf + (size_t)((t + 1) & 1) * 32768
                                  + (size_t)(bg + b) * 512 + j0 + j);
                __hip_atomic_store(dst, pk, __ATOMIC_RELAXED, __HIP_MEMORY_SCOPE_AGENT);
            }
        }

        if (t < T_ - 1) {
            __syncthreads();   // drains vmcnt: all agent-scope h stores complete
            if (tid == 0) {
                __hip_atomic_fetch_add(myc, 1u, __ATOMIC_RELAXED, __HIP_MEMORY_SCOPE_AGENT);
                unsigned target = 32u * (unsigned)(t + 1);
                while (__hip_atomic_load(myc, __ATOMIC_RELAXED, __HIP_MEMORY_SCOPE_AGENT) < target) {}
            }
            __syncthreads();
        }
    }
    hmean[(size_t)(bg + b) * 512 + j0 + j] = hsum * (1.f / 1024.f);
}

// ---------------------------------------------------------------------------
// Kernel 5: preds = sigmoid(hmean @ W_dense + b_dense), one wave per batch row
// ---------------------------------------------------------------------------
__global__ void dense_out(const float* __restrict__ hmean, const float* __restrict__ Wd,
                          const float* __restrict__ bd, float* __restrict__ out) {
    int bb = blockIdx.x;
    int lane = threadIdx.x;
    float p = 0.f;
    for (int e = lane; e < H_; e += 64) p += hmean[(size_t)bb * H_ + e] * Wd[e];
#pragma unroll
    for (int off = 32; off; off >>= 1) p += __shfl_down(p, off);
    if (lane == 0) out[bb] = 1.f / (1.f + __expf(-(p + bd[0])));
}

// ---------------------------------------------------------------------------
extern "C" void kernel_launch(void* const* d_in, const int* in_sizes, int n_in,
                              void* d_out, int out_size, void* d_ws, size_t ws_size,
                              hipStream_t stream) {
    const float* essays  = (const float*)d_in[0];
    const float* W_lstm  = (const float*)d_in[1];
    const float* b_lstm  = (const float*)d_in[2];
    const float* W_dense = (const float*)d_in[3];
    const float* b_dense = (const float*)d_in[4];
    float* out = (float*)d_out;

    char* ws = (char*)d_ws;
    unsigned short* xp   = (unsigned short*)(ws);                   // 65536*2048*2 = 256 MB
    unsigned short* Ab   = (unsigned short*)(ws + 268435456ull);    // 65536*320*2  = 40 MB
    unsigned short* Bt   = (unsigned short*)(ws + 310378496ull);    // 2048*320*2   = 1.25 MB
    unsigned short* hbuf = (unsigned short*)(ws + 311689216ull);    // 2*64*512*2   = 128 KB
    float*          hm   = (float*)(ws + 311820288ull);             // 64*512*4     = 128 KB
    unsigned int*   cnt  = (unsigned int*)(ws + 311951360ull);      // 256*4        = 1 KB

    hipLaunchKernelGGL(cvt_essays, dim3(81920), dim3(256), 0, stream, essays, Ab);
    hipLaunchKernelGGL(cvt_misc,   dim3(2560),  dim3(256), 0, stream, W_lstm, Bt, hbuf, cnt);
    hipLaunchKernelGGL(gemm_xp,    dim3(8192),  dim3(256), 0, stream, Ab, Bt, b_lstm, xp);
    hipLaunchKernelGGL(lstm_rec,   dim3(128),   dim3(256), 0, stream, W_lstm, xp, hbuf, hm, cnt);
    hipLaunchKernelGGL(dense_out,  dim3(64),    dim3(64),  0, stream, hm, W_dense, b_dense, out);
}